// Round 3
// baseline (2002.606 us; speedup 1.0000x reference)
//
#include <hip/hip_runtime.h>

// Problem constants (fixed by the reference)
constexpr int Mdim = 32;      // b*c
constexpr int Kdim = 16384;   // rows*cols
constexpr int Ndim = 16384;   // h*w

constexpr int TPB  = 256;
constexpr int NPT  = 2;                  // columns per thread (float2)
constexpr int NT   = TPB * NPT;          // 512 columns per block
constexpr int NTILES = Ndim / NT;        // 32
constexpr int KT   = 32;                 // k-chunks (split-K factor)
constexpr int KC   = Kdim / KT;          // 512 k's per block
constexpr int SKC  = 128;                // k's per LDS sub-chunk (16 KB)
constexpr int NSUB = KC / SKC;           // 4 sub-chunks
constexpr int U    = 4;                  // V prefetch ring depth

// ---------------------------------------------------------------------------
// Phase 0: xT[k][m] = relu(image[m][k]) / 128   (2 MB, built once per launch)
// ---------------------------------------------------------------------------
__global__ __launch_bounds__(TPB)
void build_xt(const float* __restrict__ image, float* __restrict__ xT) {
    const int t = blockIdx.x * TPB + threadIdx.x;   // t in [0, K*M)
    const int k = t >> 5;
    const int m = t & 31;
    const float v = image[(size_t)m * Kdim + k];
    xT[t] = fmaxf(v, 0.0f) * (1.0f / 128.0f);
}

// ---------------------------------------------------------------------------
// Phase 1: split-K GEMM.
//  - x sub-chunk (128 k x 32 m fp32 = 16 KB) double-buffered in LDS,
//    read via ds_read_b128 broadcast (same addr across lanes -> conflict-free)
//  - V streamed as float2/lane with a 4-deep prefetch ring
//  - acc: 32 m x float2 = 64 VGPRs; __launch_bounds__(256,4) caps at 128 VGPR
//    -> 4 blocks/CU = 16 waves/CU; grid = 1024 = exactly 4 blocks/CU
// ---------------------------------------------------------------------------
__global__ __launch_bounds__(TPB, 4)
void ht_gemm(const float* __restrict__ xT,     // (K, 32) relu'd, scaled
             const float* __restrict__ vote,   // (K, N) row-major
             float* __restrict__ parts)        // (KT, 32, N) partials
{
    __shared__ float xs[2][SKC * Mdim];        // 2 x 16 KB

    const int tid    = threadIdx.x;
    const int ntile  = blockIdx.x % NTILES;
    const int kchunk = blockIdx.x / NTILES;
    const int k0     = kchunk * KC;
    const int n0     = ntile * NT + tid * NPT;

    // Stage sub-chunk 0 (xT chunk is fully contiguous: coalesced float4)
    {
        const float4* src = reinterpret_cast<const float4*>(xT + (size_t)k0 * Mdim);
        float4* dst = reinterpret_cast<float4*>(xs[0]);
        #pragma unroll
        for (int i = 0; i < 4; ++i) dst[tid + TPB * i] = src[tid + TPB * i];
    }

    float2 acc[Mdim];
    #pragma unroll
    for (int m = 0; m < Mdim; ++m) acc[m] = make_float2(0.f, 0.f);

    // V prefetch ring
    const float* vp0 = vote + (size_t)k0 * Ndim + n0;
    float2 vbuf[U];
    #pragma unroll
    for (int u = 0; u < U; ++u)
        vbuf[u] = *reinterpret_cast<const float2*>(vp0 + (size_t)u * Ndim);
    const float* vpf = vp0 + (size_t)U * Ndim;  // next row to prefetch
    int kpf = k0 + U;                           // its global row index (uniform)

    for (int c = 0; c < NSUB; ++c) {
        __syncthreads();   // xs[c&1] published; xs[(c+1)&1] free to overwrite
        if (c + 1 < NSUB) {
            const float4* src = reinterpret_cast<const float4*>(
                xT + (size_t)(k0 + (c + 1) * SKC) * Mdim);
            float4* dst = reinterpret_cast<float4*>(xs[(c + 1) & 1]);
            #pragma unroll
            for (int i = 0; i < 4; ++i) dst[tid + TPB * i] = src[tid + TPB * i];
        }

        const float* xbase = xs[c & 1];
        #pragma unroll 4
        for (int kk = 0; kk < SKC; ++kk) {
            const float2 v = vbuf[kk & (U - 1)];
            // prefetch k+U (clamped at Kdim-1; clamped rows are never consumed)
            vbuf[kk & (U - 1)] = *reinterpret_cast<const float2*>(vpf);
            const bool adv = (kpf < Kdim - 1);
            vpf += adv ? (size_t)Ndim : 0;
            kpf += adv ? 1 : 0;

            const float4* xrow = reinterpret_cast<const float4*>(xbase + kk * Mdim);
            #pragma unroll
            for (int g = 0; g < 8; ++g) {
                const float4 xv = xrow[g];    // ds_read_b128 broadcast
                acc[4 * g + 0].x = fmaf(xv.x, v.x, acc[4 * g + 0].x);
                acc[4 * g + 0].y = fmaf(xv.x, v.y, acc[4 * g + 0].y);
                acc[4 * g + 1].x = fmaf(xv.y, v.x, acc[4 * g + 1].x);
                acc[4 * g + 1].y = fmaf(xv.y, v.y, acc[4 * g + 1].y);
                acc[4 * g + 2].x = fmaf(xv.z, v.x, acc[4 * g + 2].x);
                acc[4 * g + 2].y = fmaf(xv.z, v.y, acc[4 * g + 2].y);
                acc[4 * g + 3].x = fmaf(xv.w, v.x, acc[4 * g + 3].x);
                acc[4 * g + 3].y = fmaf(xv.w, v.y, acc[4 * g + 3].y);
            }
        }
    }

    float* p = parts + ((size_t)kchunk * Mdim) * Ndim + n0;
    #pragma unroll
    for (int m = 0; m < Mdim; ++m)
        *reinterpret_cast<float2*>(p + (size_t)m * Ndim) = acc[m];
}

// ---------------------------------------------------------------------------
// Phase 2: out[i] = sum_c parts[c][i]  (float4 per thread, coalesced)
// ---------------------------------------------------------------------------
__global__ __launch_bounds__(TPB)
void ht_reduce(const float* __restrict__ parts, float* __restrict__ out, int nchunks) {
    const size_t i4 = (size_t)blockIdx.x * TPB + threadIdx.x;   // float4 index
    const float4* p = reinterpret_cast<const float4*>(parts) + i4;
    float4 s = make_float4(0.f, 0.f, 0.f, 0.f);
    constexpr size_t stride4 = (size_t)Mdim * Ndim / 4;
    for (int c = 0; c < nchunks; ++c) {
        const float4 v = p[(size_t)c * stride4];
        s.x += v.x; s.y += v.y; s.z += v.z; s.w += v.w;
    }
    reinterpret_cast<float4*>(out)[i4] = s;
}

// ---------------------------------------------------------------------------
// Fallback (tiny ws): atomic version — correct, slower.
// ---------------------------------------------------------------------------
__global__ __launch_bounds__(TPB)
void ht_gemm_atomic(const float* __restrict__ image, const float* __restrict__ vote,
                    float* __restrict__ out) {
    __shared__ float xsh[256 * Mdim];
    const int tid = threadIdx.x;
    const int ntile = blockIdx.x % 16;
    const int k0 = (blockIdx.x / 16) * 256;
    const int n0 = ntile * 1024 + tid * 4;
    for (int idx = tid; idx < 256 * Mdim; idx += TPB) {
        const int kk = idx >> 5, m = idx & 31;
        xsh[idx] = fmaxf(image[(size_t)m * Kdim + (k0 + kk)], 0.0f) * (1.0f / 128.0f);
    }
    __syncthreads();
    float4 acc[Mdim];
    #pragma unroll
    for (int m = 0; m < Mdim; ++m) acc[m] = make_float4(0.f, 0.f, 0.f, 0.f);
    const float* vptr = vote + (size_t)k0 * Ndim + n0;
    for (int kk = 0; kk < 256; ++kk) {
        const float4 v = *reinterpret_cast<const float4*>(vptr);
        vptr += Ndim;
        #pragma unroll
        for (int m = 0; m < Mdim; ++m) {
            const float s = xsh[kk * Mdim + m];
            acc[m].x = fmaf(s, v.x, acc[m].x); acc[m].y = fmaf(s, v.y, acc[m].y);
            acc[m].z = fmaf(s, v.z, acc[m].z); acc[m].w = fmaf(s, v.w, acc[m].w);
        }
    }
    #pragma unroll
    for (int m = 0; m < Mdim; ++m) {
        float* o = out + (size_t)m * Ndim + n0;
        unsafeAtomicAdd(o + 0, acc[m].x); unsafeAtomicAdd(o + 1, acc[m].y);
        unsafeAtomicAdd(o + 2, acc[m].z); unsafeAtomicAdd(o + 3, acc[m].w);
    }
}

extern "C" void kernel_launch(void* const* d_in, const int* in_sizes, int n_in,
                              void* d_out, int out_size, void* d_ws, size_t ws_size,
                              hipStream_t stream) {
    const float* image = (const float*)d_in[0];   // (32, 16384)
    const float* vote  = (const float*)d_in[1];   // (16384, 16384)
    float* out = (float*)d_out;                   // (32, 16384)

    const size_t xt_bytes    = (size_t)Kdim * Mdim * sizeof(float);   // 2 MB
    const size_t chunk_bytes = (size_t)Mdim * Ndim * sizeof(float);   // 2 MB

    if (xt_bytes + (size_t)KT * chunk_bytes > ws_size) {
        // ws too small for split-K partials: atomic fallback.
        (void)hipMemsetAsync(out, 0, (size_t)out_size * sizeof(float), stream);
        ht_gemm_atomic<<<dim3(16 * 64), TPB, 0, stream>>>(image, vote, out);
        return;
    }

    float* xT    = (float*)d_ws;
    float* parts = (float*)((char*)d_ws + xt_bytes);

    build_xt<<<dim3((Kdim * Mdim) / TPB), TPB, 0, stream>>>(image, xT);
    ht_gemm<<<dim3(NTILES * KT), TPB, 0, stream>>>(xT, vote, parts);
    ht_reduce<<<dim3((Mdim * Ndim) / (4 * TPB)), TPB, 0, stream>>>(parts, out, KT);
}

// Round 5
// 1329.200 us; speedup vs baseline: 1.5066x; 1.5066x over previous
//
#include <hip/hip_runtime.h>

// Problem constants (fixed by the reference)
constexpr int Mdim = 32;      // b*c
constexpr int Kdim = 16384;   // rows*cols
constexpr int Ndim = 16384;   // h*w

constexpr int TPB = 256;

// GEMM tiling
constexpr int NB      = 128;            // n-columns per block
constexpr int NTILES  = Ndim / NB;      // 128
constexpr int KT      = 8;              // split-K chunks
constexpr int KC      = Kdim / KT;      // 2048 k per block
constexpr int KB      = 64;             // k-rows per LDS buffer
constexpr int NCHUNK  = KC / KB;        // 32
constexpr int LROW    = 132;            // shorts per LDS row (264 B, pad vs 128)

typedef short bf16x8 __attribute__((ext_vector_type(8)));   // 8 bf16 (guide §3)
typedef float f32x4  __attribute__((ext_vector_type(4)));

// fp32 -> bf16, round-to-nearest-even (pure integer; no HIP class types)
__device__ __forceinline__ short f32_to_bf16(float f) {
    union { float f; unsigned u; } c; c.f = f;
    unsigned u = c.u;
    u += 0x7fffu + ((u >> 16) & 1u);
    return (short)(u >> 16);
}

// ---------------------------------------------------------------------------
// Phase 0: build A-fragments of x in MFMA 16x16x32 layout, bf16.
// frag id f = kc*2 + mt (kc = k/32, mt = m-tile 0/1); lane holds 8 bf16:
//   A[m = mt*16 + (lane&15)][k = kc*32 + (lane>>4)*8 + j],  scaled by 1/128.
// xa[(f*64 + lane)*8 + j]
// ---------------------------------------------------------------------------
__global__ __launch_bounds__(TPB)
void build_xa(const float* __restrict__ image, short* __restrict__ xa) {
    const int g    = blockIdx.x * TPB + threadIdx.x;   // 0 .. 65535
    const int lane = g & 63;
    const int frag = g >> 6;                           // 0 .. 1023
    const int mt   = frag & 1;
    const int kc   = frag >> 1;
    const int m    = mt * 16 + (lane & 15);
    const int k    = kc * 32 + (lane >> 4) * 8;
    const float* src = image + (size_t)m * Kdim + k;

    bf16x8 o;
    #pragma unroll
    for (int j = 0; j < 8; ++j)
        o[j] = f32_to_bf16(fmaxf(src[j], 0.0f) * (1.0f / 128.0f));
    reinterpret_cast<bf16x8*>(xa)[g] = o;
}

// ---------------------------------------------------------------------------
// Phase 1: split-K MFMA GEMM.  Block = 256 thr = 4 waves; wave w owns columns
// [n0 + w*32, +32) as two 16-col fragments. V staged fp32->bf16 into LDS,
// rows XOR-swizzled by ((row>>3)&3)*16 columns so the columnar B-frag reads
// (8 x ds_read_u16, stride LROW) put the 4 quads on disjoint bank octets.
// ---------------------------------------------------------------------------
__global__ __launch_bounds__(TPB)
void ht_gemm(const short* __restrict__ xa,    // A-fragments (bf16)
             const float* __restrict__ vote,  // (K, N) fp32
             float* __restrict__ parts)       // (KT, 32, N) fp32 partials
{
    __shared__ short lds[2][KB * LROW];       // 2 x 16.9 KB

    const int tid    = threadIdx.x;
    const int lane   = tid & 63;
    const int w      = tid >> 6;
    const int ntile  = blockIdx.x & (NTILES - 1);
    const int kchunk = blockIdx.x >> 7;       // / NTILES
    const int k0     = kchunk * KC;
    const int n0     = ntile * NB;

    // staging decomposition: thread covers rows s_k+8i, float4-col s_c4
    const int s_k  = tid >> 5;                // 0..7
    const int s_c4 = tid & 31;                // 0..31

    // B-fragment lane decomposition
    const int bq = lane >> 4;                 // quad: k-group
    const int bn = lane & 15;                 // n within 16

    f32x4 acc[2][2];                          // [mt][cl]
    #pragma unroll
    for (int a = 0; a < 2; ++a)
        #pragma unroll
        for (int b = 0; b < 2; ++b) { f32x4 z = {0.f, 0.f, 0.f, 0.f}; acc[a][b] = z; }

    float4 tmp[8];                            // in-flight V tile (32 VGPRs)

    auto load_tile = [&](int ch) {
        const float* s = vote + ((size_t)(k0 + ch * KB + s_k)) * Ndim + n0 + s_c4 * 4;
        #pragma unroll
        for (int i = 0; i < 8; ++i)
            tmp[i] = *reinterpret_cast<const float4*>(s + (size_t)(i * 8) * Ndim);
    };
    auto write_tile = [&](int buf) {
        #pragma unroll
        for (int i = 0; i < 8; ++i) {
            const int kk    = i * 8 + s_k;
            const int colsw = ((s_c4 * 4) + (((kk >> 3) & 3) << 4)) & 127;
            *reinterpret_cast<short4*>(&lds[buf][kk * LROW + colsw]) =
                make_short4(f32_to_bf16(tmp[i].x), f32_to_bf16(tmp[i].y),
                            f32_to_bf16(tmp[i].z), f32_to_bf16(tmp[i].w));
        }
    };
    auto compute = [&](int buf, int ch) {
        #pragma unroll
        for (int rs = 0; rs < KB / 32; ++rs) {             // 2 k32-steps
            const int kcg = (k0 >> 5) + ch * (KB / 32) + rs;
            const bf16x8 a0 = *reinterpret_cast<const bf16x8*>(
                xa + ((size_t)(kcg * 2 + 0) * 64 + lane) * 8);
            const bf16x8 a1 = *reinterpret_cast<const bf16x8*>(
                xa + ((size_t)(kcg * 2 + 1) * 64 + lane) * 8);
            #pragma unroll
            for (int cl = 0; cl < 2; ++cl) {
                const int col   = w * 32 + cl * 16 + bn;
                const int colsw = (col + (bq << 4)) & 127;          // matches write swz
                const short* p  = &lds[buf][(rs * 32 + bq * 8) * LROW + colsw];
                bf16x8 bf;
                #pragma unroll
                for (int j = 0; j < 8; ++j) bf[j] = p[j * LROW];    // ds_read_u16 x8
                acc[0][cl] = __builtin_amdgcn_mfma_f32_16x16x32_bf16(a0, bf, acc[0][cl], 0, 0, 0);
                acc[1][cl] = __builtin_amdgcn_mfma_f32_16x16x32_bf16(a1, bf, acc[1][cl], 0, 0, 0);
            }
        }
    };

    load_tile(0);
    write_tile(0);
    for (int ch = 0; ch < NCHUNK; ++ch) {
        __syncthreads();                       // buf ch&1 published; (ch+1)&1 free
        if (ch + 1 < NCHUNK) load_tile(ch + 1);   // global loads overlap compute
        compute(ch & 1, ch);
        if (ch + 1 < NCHUNK) write_tile((ch + 1) & 1);
    }

    // Epilogue: C/D layout col = lane&15 (=bn), row = bq*4 + reg  [m89-verified]
    float* pb = parts + (size_t)kchunk * ((size_t)Mdim * Ndim);
    #pragma unroll
    for (int mt = 0; mt < 2; ++mt)
        #pragma unroll
        for (int cl = 0; cl < 2; ++cl)
            #pragma unroll
            for (int r = 0; r < 4; ++r) {
                const int row = mt * 16 + bq * 4 + r;
                const int col = n0 + w * 32 + cl * 16 + bn;
                pb[(size_t)row * Ndim + col] = acc[mt][cl][r];
            }
}

// ---------------------------------------------------------------------------
// Phase 2: out[i] = sum_c parts[c][i]
// ---------------------------------------------------------------------------
__global__ __launch_bounds__(TPB)
void ht_reduce(const float* __restrict__ parts, float* __restrict__ out, int nchunks) {
    const size_t i4 = (size_t)blockIdx.x * TPB + threadIdx.x;
    const float4* p = reinterpret_cast<const float4*>(parts) + i4;
    float4 s = make_float4(0.f, 0.f, 0.f, 0.f);
    constexpr size_t stride4 = (size_t)Mdim * Ndim / 4;
    for (int c = 0; c < nchunks; ++c) {
        const float4 v = p[(size_t)c * stride4];
        s.x += v.x; s.y += v.y; s.z += v.z; s.w += v.w;
    }
    reinterpret_cast<float4*>(out)[i4] = s;
}

// ---------------------------------------------------------------------------
// Fallback (tiny ws): fp32 atomic version — correct, slower.
// ---------------------------------------------------------------------------
__global__ __launch_bounds__(TPB)
void ht_gemm_atomic(const float* __restrict__ image, const float* __restrict__ vote,
                    float* __restrict__ out) {
    __shared__ float xsh[256 * Mdim];
    const int tid = threadIdx.x;
    const int ntile = blockIdx.x % 16;
    const int k0 = (blockIdx.x / 16) * 256;
    const int nn0 = ntile * 1024 + tid * 4;
    for (int idx = tid; idx < 256 * Mdim; idx += TPB) {
        const int kk = idx >> 5, m = idx & 31;
        xsh[idx] = fmaxf(image[(size_t)m * Kdim + (k0 + kk)], 0.0f) * (1.0f / 128.0f);
    }
    __syncthreads();
    float4 acc[Mdim];
    #pragma unroll
    for (int m = 0; m < Mdim; ++m) acc[m] = make_float4(0.f, 0.f, 0.f, 0.f);
    const float* vptr = vote + (size_t)k0 * Ndim + nn0;
    for (int kk = 0; kk < 256; ++kk) {
        const float4 v = *reinterpret_cast<const float4*>(vptr);
        vptr += Ndim;
        #pragma unroll
        for (int m = 0; m < Mdim; ++m) {
            const float s = xsh[kk * Mdim + m];
            acc[m].x = fmaf(s, v.x, acc[m].x); acc[m].y = fmaf(s, v.y, acc[m].y);
            acc[m].z = fmaf(s, v.z, acc[m].z); acc[m].w = fmaf(s, v.w, acc[m].w);
        }
    }
    #pragma unroll
    for (int m = 0; m < Mdim; ++m) {
        float* o = out + (size_t)m * Ndim + nn0;
        unsafeAtomicAdd(o + 0, acc[m].x); unsafeAtomicAdd(o + 1, acc[m].y);
        unsafeAtomicAdd(o + 2, acc[m].z); unsafeAtomicAdd(o + 3, acc[m].w);
    }
}

extern "C" void kernel_launch(void* const* d_in, const int* in_sizes, int n_in,
                              void* d_out, int out_size, void* d_ws, size_t ws_size,
                              hipStream_t stream) {
    const float* image = (const float*)d_in[0];   // (32, 16384)
    const float* vote  = (const float*)d_in[1];   // (16384, 16384)
    float* out = (float*)d_out;                   // (32, 16384)

    const size_t xa_bytes    = (size_t)(Kdim / 32) * 2 * 64 * 8 * sizeof(short); // 1 MB
    const size_t chunk_bytes = (size_t)Mdim * Ndim * sizeof(float);              // 2 MB

    if (xa_bytes + (size_t)KT * chunk_bytes > ws_size) {
        (void)hipMemsetAsync(out, 0, (size_t)out_size * sizeof(float), stream);
        ht_gemm_atomic<<<dim3(16 * 64), TPB, 0, stream>>>(image, vote, out);
        return;
    }

    short* xa    = (short*)d_ws;
    float* parts = (float*)((char*)d_ws + xa_bytes);

    build_xa<<<dim3((Kdim / 32) * 2 * 64 / TPB), TPB, 0, stream>>>(image, xa);
    ht_gemm<<<dim3(NTILES * KT), TPB, 0, stream>>>(xa, vote, parts);
    ht_reduce<<<dim3((Mdim * Ndim) / (4 * TPB)), TPB, 0, stream>>>(parts, out, KT);
}